// Round 11
// baseline (646.949 us; speedup 1.0000x reference)
//
#include <hip/hip_runtime.h>
#include <hip/hip_bf16.h>

typedef __hip_bfloat16 bf16;
typedef __attribute__((ext_vector_type(4))) float f32x4;
typedef __attribute__((ext_vector_type(8))) short short8;

__device__ __forceinline__ float b2f(bf16 v) { return __bfloat162float(v); }
__device__ __forceinline__ ushort f2bu(float v)
{
    bf16 b = __float2bfloat16(v);
    return *(ushort*)&b;
}
// relu on a packed pair of bf16 (zero any half with sign bit set)
__device__ __forceinline__ uint relu2(uint v)
{
    uint r = v;
    if (r & 0x8000u)     r &= 0xFFFF0000u;
    if (r & 0x80000000u) r &= 0x0000FFFFu;
    return r;
}
__device__ __forceinline__ uint packbf2(float a, float b)
{
    uint lo = f2bu(a), hi = f2bu(b);
    return lo | (hi << 16);
}

// ===========================================================================
// conv1 weight pack: wp1[kb 0..7][co 0..127][j 0..7], k = kb*8+j (OIHW inner
// index ci*16+kh*4+kw); k>=48 zero. grid 32.
// ===========================================================================
__global__ void wpack1_k(const float* __restrict__ w, bf16* __restrict__ wp)
{
    int i = blockIdx.x * 256 + threadIdx.x;        // 8192
    int j = i & 7; int co = (i >> 3) & 127; int kb = i >> 10;
    int k = kb * 8 + j;
    float v = (k < 48) ? w[co * 48 + k] : 0.f;
    wp[i] = __float2bfloat16(v);
}

// ===========================================================================
// conv1 MFMA: unchanged (passed R10).
// ===========================================================================
__global__ __launch_bounds__(256) void conv1m_k(const float* __restrict__ x,
        const bf16* __restrict__ wp1, const float* __restrict__ bias,
        bf16* __restrict__ h1T)
{
    int bid = blockIdx.x;
    int pxt = bid & 511, img = bid >> 9;
    int tr = pxt >> 4, tc = pxt & 15;
    int oh0 = tr * 8, ow0 = tc * 16;
    const float* xi = x + (size_t)img * 786432;
    bf16* oT = h1T + (size_t)img * 8388608;

    int t = threadIdx.x;
    int wave = t >> 6, lane = t & 63;
    int quad = lane >> 4, l15 = lane & 15;

    __shared__ ushort xs[4 * 640];
    __shared__ ushort ot[128 * 136];

    int ihb = oh0 * 2 - 1, iwb = ow0 * 2 - 1;
    for (int i = t; i < 1836; i += 256) {
        int ci = i / 612; int r1 = i - ci * 612;
        int ihl = r1 / 34, iwl = r1 - ihl * 34;
        int ih = ihb + ihl, iw = iwb + iwl;
        float v = 0.f;
        if ((unsigned)ih < 512u && (unsigned)iw < 512u)
            v = xi[ci * 262144 + ih * 512 + iw];
        xs[ci * 640 + ihl * 35 + iwl] = f2bu(v);
    }
    for (int i = t; i < 640; i += 256) xs[3 * 640 + i] = 0;
    __syncthreads();

    f32x4 zero = {0.f, 0.f, 0.f, 0.f};
    f32x4 acc[8][2];
    #pragma unroll
    for (int m = 0; m < 8; ++m) { acc[m][0] = zero; acc[m][1] = zero; }

    int ci_b = quad >> 1;
    int kh0 = (quad & 1) * 2;
    int iwl0 = 2 * l15;

    #pragma unroll
    for (int ks = 0; ks < 2; ++ks) {
        union { short8 v; uint u[4]; } b[2];
        #pragma unroll
        for (int nt = 0; nt < 2; ++nt) {
            int py = wave * 2 + nt;
            int base = (ks * 2 + ci_b) * 640 + (2 * py + kh0) * 35 + iwl0;
            b[nt].u[0] = *(const uint*)&xs[base];
            b[nt].u[1] = *(const uint*)&xs[base + 2];
            b[nt].u[2] = *(const uint*)&xs[base + 35];
            b[nt].u[3] = *(const uint*)&xs[base + 37];
        }
        const bf16* abase = wp1 + ((size_t)(ks * 4 + quad) * 128 + l15) * 8;
        #pragma unroll
        for (int m = 0; m < 8; ++m) {
            short8 a = *(const short8*)(abase + m * 16 * 8);
            acc[m][0] = __builtin_amdgcn_mfma_f32_16x16x32_bf16(a, b[0].v, acc[m][0], 0, 0, 0);
            acc[m][1] = __builtin_amdgcn_mfma_f32_16x16x32_bf16(a, b[1].v, acc[m][1], 0, 0, 0);
        }
    }

    #pragma unroll
    for (int m = 0; m < 8; ++m) {
        int cobase = m * 16 + quad * 4;
        float b0 = bias[cobase], b1 = bias[cobase + 1];
        float b2 = bias[cobase + 2], b3 = bias[cobase + 3];
        #pragma unroll
        for (int nt = 0; nt < 2; ++nt) {
            int pxl = (wave * 2 + nt) * 16 + l15;
            uint w0 = packbf2(fmaxf(b0 + acc[m][nt][0], 0.f),
                              fmaxf(b1 + acc[m][nt][1], 0.f));
            uint w1 = packbf2(fmaxf(b2 + acc[m][nt][2], 0.f),
                              fmaxf(b3 + acc[m][nt][3], 0.f));
            *(uint*)&ot[pxl * 136 + cobase]     = w0;
            *(uint*)&ot[pxl * 136 + cobase + 2] = w1;
        }
    }
    __syncthreads();
    {
        int pxl = t >> 1, half = t & 1;
        int oh = oh0 + (pxl >> 4), ow = ow0 + (pxl & 15);
        const uint4* src = (const uint4*)&ot[pxl * 136 + half * 64];
        uint4* dst = (uint4*)(oT + ((size_t)(oh * 256 + ow)) * 128 + half * 64);
        #pragma unroll
        for (int i = 0; i < 8; ++i) dst[i] = src[i];
    }
}

// ===========================================================================
// weight pack (7x7 convs): wpack[tap 0..49][ci>>3][co 0..255][ci&7] bf16,
// tap 49 = zeros (K-pad for tap-pair ksteps).
// ===========================================================================
template <int CI>
__global__ void wpack_k(const float* __restrict__ w, bf16* __restrict__ wp)
{
    int i = blockIdx.x * 256 + threadIdx.x;
    int cil = i & 7; int co = (i >> 3) & 255; int r = i >> 11;
    int cib8 = r % (CI / 8); int tap = r / (CI / 8);
    float v = 0.f;
    if (tap < 49) v = w[co * (CI * 49) + (cib8 * 8 + cil) * 49 + tap];
    wp[i] = __float2bfloat16(v);
}

// generic pack: OIHW f32 [CO][CIB8*8][KT] -> [tap][cib8][co][8] bf16
template <int KT, int CO, int CIB8>
__global__ void wpack_g(const float* __restrict__ w, bf16* __restrict__ wp)
{
    int i = blockIdx.x * 256 + threadIdx.x;
    int cil = i & 7; int co = (i >> 3) & (CO - 1);
    int r = (i >> 3) / CO;
    int cib8 = r % CIB8; int tap = r / CIB8;
    wp[i] = __float2bfloat16(w[(size_t)co * (CIB8 * 8 * KT) + (cib8 * 8 + cil) * KT + tap]);
}

// ===========================================================================
// implicit-GEMM MFMA 7x7 s4 p2 conv, v3: chunk = 16 ci, kstep = 2 taps x
// 16 ci (tap_par = quad>>1, ci_half = quad&1; tap 49 = zero-A pad).
// LDS pt3[posp][12 uints]: lane's 8 ci are 4 contiguous uints, 16B aligned
// -> B-frag = ONE ds_read_b128 (vs 4x ds_read_b32 in v2). Bank starts
// (12*posp+4g) mod 32 stride 12 -> <=2-way (free). LDS 58.8 KB.
// Column-permuted posp = r*35 + (c&3)*9 + (c>>2) keeps qxl->posp stride 1.
// conv2: IH=256 OH=64 CI=128 SPLIT=1 -> NHWC bf16, bias+relu fused.
// conv3: IH=64 OH=16 CI=256 SPLIT=8 -> f32 atomic partials.
// ===========================================================================
template <int IH, int OH, int CI, int SPLIT, bool WRITE_T>
__global__ __launch_bounds__(256) void conv_mfma3_k(
        const bf16* __restrict__ inT, const bf16* __restrict__ wpack,
        const float* __restrict__ bias, float* __restrict__ outA,
        bf16* __restrict__ outT)
{
    constexpr int TPD = OH / 8;
    constexpr int NT = TPD * TPD;
    constexpr int CPB = (CI / 16) / SPLIT;     // 16-ci chunks per block
    constexpr int CIB8 = CI / 8;

    int bid = blockIdx.x;
    int pxt = bid % NT;
    int rest = bid / NT;
    int img = rest & 7;
    int split = rest >> 3;
    int oh0 = (pxt / TPD) * 8, ow0 = (pxt % TPD) * 8;

    int t = threadIdx.x;
    int wave = t >> 6, lane = t & 63;
    int quad = lane >> 4, l15 = lane & 15;

    const bf16* inb = inT + (size_t)img * ((size_t)IH * IH * CI);

    __shared__ __align__(16) uint pt3[1225 * 12];  // 58.8 KB

    f32x4 zero = {0.f, 0.f, 0.f, 0.f};
    f32x4 acc[4][4];
    #pragma unroll
    for (int a = 0; a < 4; ++a)
        #pragma unroll
        for (int b = 0; b < 4; ++b) acc[a][b] = zero;

    int ihb = oh0 * 4 - 2, iwb = ow0 * 4 - 2;
    int qxl = l15 & 7, pyl = l15 >> 3;
    int tap_par = quad >> 1, ci_half = quad & 1;

    for (int cc = 0; cc < CPB; ++cc) {
        int ch = split * CPB + cc;
        __syncthreads();
        for (int i = t; i < 2450; i += 256) {
            int pos = i >> 1, half = i & 1;
            int r = pos / 35, c = pos - r * 35;
            int ih = ihb + r, iw = iwb + c;
            uint4 v = make_uint4(0u, 0u, 0u, 0u);
            if ((unsigned)ih < (unsigned)IH && (unsigned)iw < (unsigned)IH)
                v = *(const uint4*)(inb + ((size_t)(ih * IH + iw) * CI + ch * 16 + half * 8));
            int posp = r * 35 + (c & 3) * 9 + (c >> 2);
            *(uint4*)&pt3[posp * 12 + half * 4] = v;
        }
        __syncthreads();

        const bf16* abase = wpack +
            ((size_t)(ch * 2 + ci_half) * 256 + wave * 64 + l15) * 8;
        for (int tp = 0; tp < 25; ++tp) {
            int tap = 2 * tp + tap_par;            // tap 49: A = 0 (pad)
            short8 a[4];
            #pragma unroll
            for (int ct = 0; ct < 4; ++ct)
                a[ct] = *(const short8*)(abase +
                    ((size_t)tap * CIB8 * 256 + ct * 16) * 8);

            int tapc = min(tap, 48);
            int kh = tapc / 7, kw = tapc - kh * 7;
            int c = qxl * 4 + kw;
            int pbase = kh * 35 + (c & 3) * 9 + (c >> 2) + pyl * 140;
            #pragma unroll
            for (int pt = 0; pt < 4; ++pt) {
                int posp = pbase + pt * 280;
                short8 b = *(const short8*)&pt3[posp * 12 + ci_half * 4];
                #pragma unroll
                for (int ct = 0; ct < 4; ++ct)
                    acc[ct][pt] = __builtin_amdgcn_mfma_f32_16x16x32_bf16(
                        a[ct], b, acc[ct][pt], 0, 0, 0);
            }
        }
    }

    #pragma unroll
    for (int ct = 0; ct < 4; ++ct) {
        int cobase = wave * 64 + ct * 16 + quad * 4;
        #pragma unroll
        for (int pt = 0; pt < 4; ++pt) {
            int px = pt * 16 + l15;
            int oh = oh0 + (px >> 3), ow = ow0 + (px & 7);
            #pragma unroll
            for (int r = 0; r < 4; ++r) {
                int co = cobase + r;
                float v = acc[ct][pt][r];
                if (WRITE_T) {
                    float o = fmaxf(bias[co] + v, 0.f);
                    outT[(size_t)img * (OH * OH * 256) + (size_t)(oh * OH + ow) * 256 + co]
                        = __float2bfloat16(o);
                } else {
                    atomicAdd(&outA[(size_t)img * (OH * OH * 256) + (size_t)co * (OH * OH)
                                    + oh * OH + ow], v);
                }
            }
        }
    }
}

// combine3 -> NHWC bf16
__global__ void combine3_k(const float* __restrict__ p3, const float* __restrict__ bias,
                           bf16* __restrict__ h3T)
{
    int idx = blockIdx.x * 256 + threadIdx.x;
    int px = idx & 255;
    int co = (idx >> 8) & 255;
    int img = idx >> 16;
    float v = fmaxf(bias[co] + p3[idx], 0.f);
    h3T[((size_t)img * 256 + px) * 256 + co] = __float2bfloat16(v);
}

// ===========================================================================
// conv4 MFMA: 3x3 s2 p1, 256->256 ch, 16->8, NHWC bf16, relu. grid 8.
// ===========================================================================
__global__ __launch_bounds__(256) void conv4m_k(const bf16* __restrict__ h3T,
        const bf16* __restrict__ wp4, const float* __restrict__ bias,
        bf16* __restrict__ h4T)
{
    int img = blockIdx.x;
    int t = threadIdx.x;
    int wave = t >> 6, lane = t & 63;
    int quad = lane >> 4, l15 = lane & 15;

    __shared__ uint pt[16 * 325];

    for (int i = t; i < 16 * 325; i += 256) pt[i] = 0;

    f32x4 zero = {0.f, 0.f, 0.f, 0.f};
    f32x4 acc[4][4];
    #pragma unroll
    for (int a = 0; a < 4; ++a)
        #pragma unroll
        for (int b = 0; b < 4; ++b) acc[a][b] = zero;

    const bf16* inb = h3T + (size_t)img * 65536;

    for (int ch = 0; ch < 8; ++ch) {
        __syncthreads();
        for (int e = t; e < 4096; e += 256) {
            int cp = e & 15, px = e >> 4;
            int py = px >> 4, qx = px & 15;
            uint v = *(const uint*)(inb + (size_t)px * 256 + ch * 32 + cp * 2);
            pt[cp * 325 + (py + 1) * 18 + qx + 1] = v;
        }
        __syncthreads();

        for (int tap = 0; tap < 9; ++tap) {
            int kh = tap / 3, kw = tap - kh * 3;
            const bf16* abase = wp4 + ((size_t)((tap * 32 + ch * 4 + quad) * 256)
                                       + wave * 64 + l15) * 8;
            short8 a[4];
            #pragma unroll
            for (int ct = 0; ct < 4; ++ct)
                a[ct] = *(const short8*)(abase + ct * 16 * 8);
            #pragma unroll
            for (int pq = 0; pq < 4; ++pq) {
                int pyo = 2 * pq + (l15 >> 3);
                int ipos = (2 * pyo + kh) * 18 + 2 * (l15 & 7) + kw;
                union { short8 v; uint u[4]; } b;
                b.u[0] = pt[(quad * 4 + 0) * 325 + ipos];
                b.u[1] = pt[(quad * 4 + 1) * 325 + ipos];
                b.u[2] = pt[(quad * 4 + 2) * 325 + ipos];
                b.u[3] = pt[(quad * 4 + 3) * 325 + ipos];
                #pragma unroll
                for (int ct = 0; ct < 4; ++ct)
                    acc[ct][pq] = __builtin_amdgcn_mfma_f32_16x16x32_bf16(
                        a[ct], b.v, acc[ct][pq], 0, 0, 0);
            }
        }
    }

    #pragma unroll
    for (int ct = 0; ct < 4; ++ct) {
        int cobase = wave * 64 + ct * 16 + quad * 4;
        #pragma unroll
        for (int pq = 0; pq < 4; ++pq) {
            int px = pq * 16 + l15;
            #pragma unroll
            for (int r = 0; r < 4; ++r) {
                int co = cobase + r;
                float v = fmaxf(bias[co] + acc[ct][pq][r], 0.f);
                h4T[((size_t)img * 64 + px) * 256 + co] = __float2bfloat16(v);
            }
        }
    }
}

// ===========================================================================
// res-a MFMA: t1 = conv1x3(relu(h)), 256->1024. grid 32.
// ===========================================================================
__global__ __launch_bounds__(256) void resam_k(const bf16* __restrict__ hT,
        const bf16* __restrict__ wpA, bf16* __restrict__ t1T)
{
    int bid = blockIdx.x;
    int img = bid >> 2, g = bid & 3;
    int t = threadIdx.x;
    int wave = t >> 6, lane = t & 63;
    int quad = lane >> 4, l15 = lane & 15;

    __shared__ uint ph[128 * 81];

    for (int i = t; i < 128 * 81; i += 256) ph[i] = 0;
    __syncthreads();
    const bf16* inb = hT + (size_t)img * 16384;
    for (int e = t; e < 8192; e += 256) {
        int cp = e & 127, px = e >> 7;
        uint v = relu2(*(const uint*)(inb + (size_t)px * 256 + cp * 2));
        ph[cp * 81 + (px >> 3) * 10 + (px & 7) + 1] = v;
    }
    __syncthreads();

    f32x4 zero = {0.f, 0.f, 0.f, 0.f};
    f32x4 acc[4][4];
    #pragma unroll
    for (int a = 0; a < 4; ++a)
        #pragma unroll
        for (int b = 0; b < 4; ++b) acc[a][b] = zero;

    for (int ch = 0; ch < 8; ++ch) {
        for (int tap = 0; tap < 3; ++tap) {
            const bf16* abase = wpA + ((size_t)(tap * 32 + ch * 4 + quad) * 1024
                                       + g * 256 + wave * 64 + l15) * 8;
            short8 a[4];
            #pragma unroll
            for (int ct = 0; ct < 4; ++ct)
                a[ct] = *(const short8*)(abase + ct * 16 * 8);
            #pragma unroll
            for (int pq = 0; pq < 4; ++pq) {
                int py = 2 * pq + (l15 >> 3);
                int pos = py * 10 + (l15 & 7) + tap;
                union { short8 v; uint u[4]; } b;
                b.u[0] = ph[(ch * 16 + quad * 4 + 0) * 81 + pos];
                b.u[1] = ph[(ch * 16 + quad * 4 + 1) * 81 + pos];
                b.u[2] = ph[(ch * 16 + quad * 4 + 2) * 81 + pos];
                b.u[3] = ph[(ch * 16 + quad * 4 + 3) * 81 + pos];
                #pragma unroll
                for (int ct = 0; ct < 4; ++ct)
                    acc[ct][pq] = __builtin_amdgcn_mfma_f32_16x16x32_bf16(
                        a[ct], b.v, acc[ct][pq], 0, 0, 0);
            }
        }
    }

    #pragma unroll
    for (int ct = 0; ct < 4; ++ct) {
        int cobase = g * 256 + wave * 64 + ct * 16 + quad * 4;
        #pragma unroll
        for (int pq = 0; pq < 4; ++pq) {
            int px = pq * 16 + l15;
            #pragma unroll
            for (int r = 0; r < 4; ++r)
                t1T[((size_t)img * 64 + px) * 1024 + cobase + r]
                    = __float2bfloat16(acc[ct][pq][r]);
        }
    }
}

// ===========================================================================
// res-b MFMA: h_new = h_old + conv1x1(relu(t1)), 1024->256. grid 8.
// ===========================================================================
__global__ __launch_bounds__(256) void resbm_k(const bf16* __restrict__ holdT,
        const bf16* __restrict__ t1T, const bf16* __restrict__ wpB,
        bf16* __restrict__ hnewT)
{
    int img = blockIdx.x;
    int t = threadIdx.x;
    int wave = t >> 6, lane = t & 63;
    int quad = lane >> 4, l15 = lane & 15;

    __shared__ uint pb[256 * 65];

    f32x4 zero = {0.f, 0.f, 0.f, 0.f};
    f32x4 acc[4][4];
    #pragma unroll
    for (int a = 0; a < 4; ++a)
        #pragma unroll
        for (int b = 0; b < 4; ++b) acc[a][b] = zero;

    const bf16* inb = t1T + (size_t)img * 65536;

    for (int s = 0; s < 2; ++s) {
        __syncthreads();
        for (int e = t; e < 16384; e += 256) {
            int cp = e & 255, px = e >> 8;
            uint v = relu2(*(const uint*)(inb + (size_t)px * 1024 + s * 512 + cp * 2));
            pb[cp * 65 + px] = v;
        }
        __syncthreads();

        for (int chl = 0; chl < 16; ++chl) {
            int ch = s * 16 + chl;
            const bf16* abase = wpB + ((size_t)(ch * 4 + quad) * 256
                                       + wave * 64 + l15) * 8;
            short8 a[4];
            #pragma unroll
            for (int ct = 0; ct < 4; ++ct)
                a[ct] = *(const short8*)(abase + ct * 16 * 8);
            #pragma unroll
            for (int pq = 0; pq < 4; ++pq) {
                int px = pq * 16 + l15;
                union { short8 v; uint u[4]; } b;
                b.u[0] = pb[(chl * 16 + quad * 4 + 0) * 65 + px];
                b.u[1] = pb[(chl * 16 + quad * 4 + 1) * 65 + px];
                b.u[2] = pb[(chl * 16 + quad * 4 + 2) * 65 + px];
                b.u[3] = pb[(chl * 16 + quad * 4 + 3) * 65 + px];
                #pragma unroll
                for (int ct = 0; ct < 4; ++ct)
                    acc[ct][pq] = __builtin_amdgcn_mfma_f32_16x16x32_bf16(
                        a[ct], b.v, acc[ct][pq], 0, 0, 0);
            }
        }
    }

    #pragma unroll
    for (int ct = 0; ct < 4; ++ct) {
        int cobase = wave * 64 + ct * 16 + quad * 4;
        #pragma unroll
        for (int pq = 0; pq < 4; ++pq) {
            int px = pq * 16 + l15;
            #pragma unroll
            for (int r = 0; r < 4; ++r) {
                int co = cobase + r;
                size_t o = ((size_t)img * 64 + px) * 256 + co;
                float v = b2f(holdT[o]) + acc[ct][pq][r];
                hnewT[o] = __float2bfloat16(v);
            }
        }
    }
}

__global__ void embnorm_k(const float* __restrict__ emb, float* __restrict__ en)
{
    int k = blockIdx.x * 256 + threadIdx.x;
    const float* e = emb + (size_t)k * 256;
    float s = 0.f;
    for (int d = 0; d < 256; ++d) { float v = e[d]; s += v * v; }
    en[k] = s;
}

// VQ: one block per latent row (512). Reads h6T NHWC bf16 (relu'd here).
__global__ void vq_k(const bf16* __restrict__ h6T, const float* __restrict__ emb,
                     const float* __restrict__ en, float* __restrict__ out,
                     float* __restrict__ mse_acc, int* __restrict__ hist)
{
    int row = blockIdx.x;
    int b = row >> 6, y = (row >> 3) & 7, xx = row & 7;
    int t = threadIdx.x;
    __shared__ float lat[256];
    __shared__ float sdist[256];
    __shared__ int   sidx[256];

    float l = fmaxf(b2f(h6T[(size_t)row * 256 + t]), 0.f);
    lat[t] = l;
    __syncthreads();

    float d0 = 0.f, d1 = 0.f;
    const float* e0 = emb + (size_t)t * 256;
    const float* e1 = emb + (size_t)(t + 256) * 256;
    for (int d = 0; d < 256; ++d) {
        float lv = lat[d];
        d0 += lv * e0[d];
        d1 += lv * e1[d];
    }
    d0 = en[t] - 2.f * d0;
    d1 = en[t + 256] - 2.f * d1;
    float best_d = d0; int best_i = t;
    if (d1 < best_d) { best_d = d1; best_i = t + 256; }
    sdist[t] = best_d; sidx[t] = best_i;
    __syncthreads();
    for (int s = 128; s > 0; s >>= 1) {
        if (t < s) {
            float od = sdist[t + s]; int oi = sidx[t + s];
            if (od < sdist[t] || (od == sdist[t] && oi < sidx[t])) {
                sdist[t] = od; sidx[t] = oi;
            }
        }
        __syncthreads();
    }
    int idx = sidx[0];

    float q = emb[(size_t)idx * 256 + t];
    out[((size_t)(b * 256 + t) * 8 + y) * 8 + xx] = q;
    float diff = q - lat[t];
    __syncthreads();
    sdist[t] = diff * diff;
    __syncthreads();
    for (int s = 128; s > 0; s >>= 1) {
        if (t < s) sdist[t] += sdist[t + s];
        __syncthreads();
    }
    if (t == 0) {
        atomicAdd(mse_acc, sdist[0]);
        atomicAdd(&hist[idx], 1);
    }
}

__global__ void final_k(const float* __restrict__ mse_acc, const int* __restrict__ hist,
                        float* __restrict__ out)
{
    __shared__ float sh[512];
    int t = threadIdx.x;
    float p = (float)hist[t] / 512.f;
    sh[t] = p * logf(p + 1e-10f);
    __syncthreads();
    for (int s = 256; s > 0; s >>= 1) {
        if (t < s) sh[t] += sh[t + s];
        __syncthreads();
    }
    if (t == 0) {
        float loss = 2.f * mse_acc[0] / (512.f * 256.f);
        float perp = expf(-sh[0]);
        out[131072] = loss;
        out[131073] = perp;
    }
}

// ===========================================================================
extern "C" void kernel_launch(void* const* d_in, const int* in_sizes, int n_in,
                              void* d_out, int out_size, void* d_ws, size_t ws_size,
                              hipStream_t stream)
{
    const float* x    = (const float*)d_in[0];
    const float* w_in = (const float*)d_in[1];
    const float* b_in = (const float*)d_in[2];
    const float* w_h1 = (const float*)d_in[3];
    const float* b_h1 = (const float*)d_in[4];
    const float* w_h2 = (const float*)d_in[5];
    const float* b_h2 = (const float*)d_in[6];
    const float* w_h3 = (const float*)d_in[7];
    const float* b_h3 = (const float*)d_in[8];
    const float* r0w1 = (const float*)d_in[9];
    const float* r0w2 = (const float*)d_in[10];
    const float* r1w1 = (const float*)d_in[11];
    const float* r1w2 = (const float*)d_in[12];
    const float* emb  = (const float*)d_in[13];
    float* out = (float*)d_out;

    char* ws = (char*)d_ws;
    size_t off = 0;
    auto alloc = [&](size_t bytes) -> void* {
        void* p = ws + off;
        off += (bytes + 255) & ~(size_t)255;
        return p;
    };

    float* en  = (float*)alloc(512 * 4);
    float* mse = (float*)alloc(256);
    int*  hist = (int*)alloc(512 * 4);
    float* p3  = (float*)alloc(524288ull * 4);
    bf16* h3T  = (bf16*)alloc(524288ull * 2);
    bf16* h4T  = (bf16*)alloc(131072ull * 2);
    bf16* t1T  = (bf16*)alloc(524288ull * 2);
    bf16* h5T  = (bf16*)alloc(131072ull * 2);
    bf16* h6T  = (bf16*)alloc(131072ull * 2);
    bf16* wp1  = (bf16*)alloc(8192ull * 2);
    bf16* wpack2 = (bf16*)alloc(1638400ull * 2);
    bf16* wpack3 = (bf16*)alloc(3276800ull * 2);
    bf16* wp4  = (bf16*)alloc(589824ull * 2);
    bf16* wpA0 = (bf16*)alloc(786432ull * 2);
    bf16* wpA1 = (bf16*)alloc(786432ull * 2);
    bf16* wpB0 = (bf16*)alloc(262144ull * 2);
    bf16* wpB1 = (bf16*)alloc(262144ull * 2);
    bf16* h2T  = (bf16*)alloc(8388608ull * 2);
    size_t base_end = off;

    const size_t H1TI = 8388608;
    size_t needFull = base_end + H1TI * 8 * 2 + 4096;
    bool full = ws_size >= needFull;
    bf16* h1T = (bf16*)alloc(full ? H1TI * 8 * 2 : H1TI * 2);

    hipMemsetAsync(mse, 0, 4, stream);
    hipMemsetAsync(hist, 0, 512 * 4, stream);
    hipMemsetAsync(p3, 0, 524288ull * 4, stream);

    wpack1_k<<<32, 256, 0, stream>>>(w_in, wp1);
    wpack_k<128><<<6400, 256, 0, stream>>>(w_h1, wpack2);
    wpack_k<256><<<12800, 256, 0, stream>>>(w_h2, wpack3);
    wpack_g<9, 256, 32><<<2304, 256, 0, stream>>>(w_h3, wp4);
    wpack_g<3, 1024, 32><<<3072, 256, 0, stream>>>(r0w1, wpA0);
    wpack_g<3, 1024, 32><<<3072, 256, 0, stream>>>(r1w1, wpA1);
    wpack_g<1, 256, 128><<<1024, 256, 0, stream>>>(r0w2, wpB0);
    wpack_g<1, 256, 128><<<1024, 256, 0, stream>>>(r1w2, wpB1);

    if (full) {
        conv1m_k<<<4096, 256, 0, stream>>>(x, wp1, b_in, h1T);
        conv_mfma3_k<256, 64, 128, 1, true><<<512, 256, 0, stream>>>(
            h1T, wpack2, b_h1, nullptr, h2T);
    } else {
        for (int n = 0; n < 8; ++n) {
            conv1m_k<<<512, 256, 0, stream>>>(x + (size_t)n * 786432, wp1, b_in, h1T);
            conv_mfma3_k<256, 64, 128, 1, true><<<64, 256, 0, stream>>>(
                h1T, wpack2, b_h1, nullptr, h2T + (size_t)n * 1048576);
        }
    }

    conv_mfma3_k<64, 16, 256, 8, false><<<256, 256, 0, stream>>>(
        h2T, wpack3, b_h2, p3, nullptr);
    combine3_k<<<2048, 256, 0, stream>>>(p3, b_h2, h3T);

    conv4m_k<<<8, 256, 0, stream>>>(h3T, wp4, b_h3, h4T);
    resam_k<<<32, 256, 0, stream>>>(h4T, wpA0, t1T);
    resbm_k<<<8, 256, 0, stream>>>(h4T, t1T, wpB0, h5T);
    resam_k<<<32, 256, 0, stream>>>(h5T, wpA1, t1T);
    resbm_k<<<8, 256, 0, stream>>>(h5T, t1T, wpB1, h6T);

    embnorm_k<<<2, 256, 0, stream>>>(emb, en);
    vq_k<<<512, 256, 0, stream>>>(h6T, emb, en, out, mse, hist);
    final_k<<<1, 512, 0, stream>>>(mse, hist, out);
}

// Round 12
// 592.927 us; speedup vs baseline: 1.0911x; 1.0911x over previous
//
#include <hip/hip_runtime.h>
#include <hip/hip_bf16.h>

typedef __hip_bfloat16 bf16;
typedef __attribute__((ext_vector_type(4))) float f32x4;
typedef __attribute__((ext_vector_type(8))) short short8;

__device__ __forceinline__ float b2f(bf16 v) { return __bfloat162float(v); }
__device__ __forceinline__ ushort f2bu(float v)
{
    bf16 b = __float2bfloat16(v);
    return *(ushort*)&b;
}
// relu on a packed pair of bf16 (zero any half with sign bit set)
__device__ __forceinline__ uint relu2(uint v)
{
    uint r = v;
    if (r & 0x8000u)     r &= 0xFFFF0000u;
    if (r & 0x80000000u) r &= 0x0000FFFFu;
    return r;
}
__device__ __forceinline__ uint packbf2(float a, float b)
{
    uint lo = f2bu(a), hi = f2bu(b);
    return lo | (hi << 16);
}

// ===========================================================================
// conv1 weight pack: wp1[kb 0..7][co 0..127][j 0..7], k = kb*8+j (OIHW inner
// index ci*16+kh*4+kw); k>=48 zero. grid 32.
// ===========================================================================
__global__ void wpack1_k(const float* __restrict__ w, bf16* __restrict__ wp)
{
    int i = blockIdx.x * 256 + threadIdx.x;        // 8192
    int j = i & 7; int co = (i >> 3) & 127; int kb = i >> 10;
    int k = kb * 8 + j;
    float v = (k < 48) ? w[co * 48 + k] : 0.f;
    wp[i] = __float2bfloat16(v);
}

// ===========================================================================
// conv1 MFMA -> ci-BLOCKED bf16 h1c[img][ci16 0..7][px 0..65535][16ci].
// (Blocked layout so conv2's 16-ci staging chunks read full 64B sectors.)
// Compute identical to R10 (passed); only the final global write changed.
// ===========================================================================
__global__ __launch_bounds__(256) void conv1m_k(const float* __restrict__ x,
        const bf16* __restrict__ wp1, const float* __restrict__ bias,
        bf16* __restrict__ h1c)
{
    int bid = blockIdx.x;
    int pxt = bid & 511, img = bid >> 9;
    int tr = pxt >> 4, tc = pxt & 15;
    int oh0 = tr * 8, ow0 = tc * 16;
    const float* xi = x + (size_t)img * 786432;
    bf16* oT = h1c + (size_t)img * 8388608;

    int t = threadIdx.x;
    int wave = t >> 6, lane = t & 63;
    int quad = lane >> 4, l15 = lane & 15;

    __shared__ ushort xs[4 * 640];
    __shared__ ushort ot[128 * 136];

    int ihb = oh0 * 2 - 1, iwb = ow0 * 2 - 1;
    for (int i = t; i < 1836; i += 256) {
        int ci = i / 612; int r1 = i - ci * 612;
        int ihl = r1 / 34, iwl = r1 - ihl * 34;
        int ih = ihb + ihl, iw = iwb + iwl;
        float v = 0.f;
        if ((unsigned)ih < 512u && (unsigned)iw < 512u)
            v = xi[ci * 262144 + ih * 512 + iw];
        xs[ci * 640 + ihl * 35 + iwl] = f2bu(v);
    }
    for (int i = t; i < 640; i += 256) xs[3 * 640 + i] = 0;
    __syncthreads();

    f32x4 zero = {0.f, 0.f, 0.f, 0.f};
    f32x4 acc[8][2];
    #pragma unroll
    for (int m = 0; m < 8; ++m) { acc[m][0] = zero; acc[m][1] = zero; }

    int ci_b = quad >> 1;
    int kh0 = (quad & 1) * 2;
    int iwl0 = 2 * l15;

    #pragma unroll
    for (int ks = 0; ks < 2; ++ks) {
        union { short8 v; uint u[4]; } b[2];
        #pragma unroll
        for (int nt = 0; nt < 2; ++nt) {
            int py = wave * 2 + nt;
            int base = (ks * 2 + ci_b) * 640 + (2 * py + kh0) * 35 + iwl0;
            b[nt].u[0] = *(const uint*)&xs[base];
            b[nt].u[1] = *(const uint*)&xs[base + 2];
            b[nt].u[2] = *(const uint*)&xs[base + 35];
            b[nt].u[3] = *(const uint*)&xs[base + 37];
        }
        const bf16* abase = wp1 + ((size_t)(ks * 4 + quad) * 128 + l15) * 8;
        #pragma unroll
        for (int m = 0; m < 8; ++m) {
            short8 a = *(const short8*)(abase + m * 16 * 8);
            acc[m][0] = __builtin_amdgcn_mfma_f32_16x16x32_bf16(a, b[0].v, acc[m][0], 0, 0, 0);
            acc[m][1] = __builtin_amdgcn_mfma_f32_16x16x32_bf16(a, b[1].v, acc[m][1], 0, 0, 0);
        }
    }

    #pragma unroll
    for (int m = 0; m < 8; ++m) {
        int cobase = m * 16 + quad * 4;
        float b0 = bias[cobase], b1 = bias[cobase + 1];
        float b2 = bias[cobase + 2], b3 = bias[cobase + 3];
        #pragma unroll
        for (int nt = 0; nt < 2; ++nt) {
            int pxl = (wave * 2 + nt) * 16 + l15;
            uint w0 = packbf2(fmaxf(b0 + acc[m][nt][0], 0.f),
                              fmaxf(b1 + acc[m][nt][1], 0.f));
            uint w1 = packbf2(fmaxf(b2 + acc[m][nt][2], 0.f),
                              fmaxf(b3 + acc[m][nt][3], 0.f));
            *(uint*)&ot[pxl * 136 + cobase]     = w0;
            *(uint*)&ot[pxl * 136 + cobase + 2] = w1;
        }
    }
    __syncthreads();
    {
        int pxl = t >> 1, half = t & 1;
        int oh = oh0 + (pxl >> 4), ow = ow0 + (pxl & 15);
        size_t px = (size_t)(oh * 256 + ow);
        #pragma unroll
        for (int cb = 0; cb < 4; ++cb) {
            int c16 = half * 4 + cb;
            const uint4* src = (const uint4*)&ot[pxl * 136 + c16 * 16];
            uint4* dst = (uint4*)(oT + ((size_t)c16 * 65536 + px) * 16);
            dst[0] = src[0];
            dst[1] = src[1];
        }
    }
}

// ===========================================================================
// weight pack (7x7 convs): wpack[tap 0..49][ci>>3][co 0..255][ci&7] bf16,
// tap 49 = zeros (K-pad for tap-pair ksteps).
// ===========================================================================
template <int CI>
__global__ void wpack_k(const float* __restrict__ w, bf16* __restrict__ wp)
{
    int i = blockIdx.x * 256 + threadIdx.x;
    int cil = i & 7; int co = (i >> 3) & 255; int r = i >> 11;
    int cib8 = r % (CI / 8); int tap = r / (CI / 8);
    float v = 0.f;
    if (tap < 49) v = w[co * (CI * 49) + (cib8 * 8 + cil) * 49 + tap];
    wp[i] = __float2bfloat16(v);
}

// generic pack: OIHW f32 [CO][CIB8*8][KT] -> [tap][cib8][co][8] bf16
template <int KT, int CO, int CIB8>
__global__ void wpack_g(const float* __restrict__ w, bf16* __restrict__ wp)
{
    int i = blockIdx.x * 256 + threadIdx.x;
    int cil = i & 7; int co = (i >> 3) & (CO - 1);
    int r = (i >> 3) / CO;
    int cib8 = r % CIB8; int tap = r / CIB8;
    wp[i] = __float2bfloat16(w[(size_t)co * (CIB8 * 8 * KT) + (cib8 * 8 + cil) * KT + tap]);
}

// ===========================================================================
// implicit-GEMM MFMA 7x7 s4 p2 conv, v4: = v3 (b128 B-frags, 2-tap ksteps,
// pt3[posp][12] bank-spread LDS) + ci-BLOCKED input/output activations:
// in[img][ci16][NPX][16] so a 16-ci staging chunk reads 32B CONTIGUOUS
// (full sectors; v3's half-sector reads doubled FETCH_SIZE 160->303MB).
// conv2: IH=256 OH=64 CI=128 SPLIT=1 -> blocked bf16 out, bias+relu.
// conv3: IH=64 OH=16 CI=256 SPLIT=8 -> f32 atomic partials (NCHW).
// ===========================================================================
template <int IH, int OH, int CI, int SPLIT, bool WRITE_T>
__global__ __launch_bounds__(256) void conv_mfma4_k(
        const bf16* __restrict__ inC, const bf16* __restrict__ wpack,
        const float* __restrict__ bias, float* __restrict__ outA,
        bf16* __restrict__ outT)
{
    constexpr int TPD = OH / 8;
    constexpr int NT = TPD * TPD;
    constexpr int CPB = (CI / 16) / SPLIT;     // 16-ci chunks per block
    constexpr int CIB8 = CI / 8;
    constexpr int NPX = IH * IH;

    int bid = blockIdx.x;
    int pxt = bid % NT;
    int rest = bid / NT;
    int img = rest & 7;
    int split = rest >> 3;
    int oh0 = (pxt / TPD) * 8, ow0 = (pxt % TPD) * 8;

    int t = threadIdx.x;
    int wave = t >> 6, lane = t & 63;
    int quad = lane >> 4, l15 = lane & 15;

    const bf16* inb = inC + (size_t)img * ((size_t)NPX * CI);

    __shared__ __align__(16) uint pt3[1225 * 12];  // 58.8 KB

    f32x4 zero = {0.f, 0.f, 0.f, 0.f};
    f32x4 acc[4][4];
    #pragma unroll
    for (int a = 0; a < 4; ++a)
        #pragma unroll
        for (int b = 0; b < 4; ++b) acc[a][b] = zero;

    int ihb = oh0 * 4 - 2, iwb = ow0 * 4 - 2;
    int qxl = l15 & 7, pyl = l15 >> 3;
    int tap_par = quad >> 1, ci_half = quad & 1;

    for (int cc = 0; cc < CPB; ++cc) {
        int ch = split * CPB + cc;
        __syncthreads();
        for (int i = t; i < 2450; i += 256) {
            int pos = i >> 1, half = i & 1;
            int r = pos / 35, c = pos - r * 35;
            int ih = ihb + r, iw = iwb + c;
            uint4 v = make_uint4(0u, 0u, 0u, 0u);
            if ((unsigned)ih < (unsigned)IH && (unsigned)iw < (unsigned)IH)
                v = *(const uint4*)(inb + ((size_t)ch * NPX + ih * IH + iw) * 16 + half * 8);
            int posp = r * 35 + (c & 3) * 9 + (c >> 2);
            *(uint4*)&pt3[posp * 12 + half * 4] = v;
        }
        __syncthreads();

        const bf16* abase = wpack +
            ((size_t)(ch * 2 + ci_half) * 256 + wave * 64 + l15) * 8;
        for (int tp = 0; tp < 25; ++tp) {
            int tap = 2 * tp + tap_par;            // tap 49: A = 0 (pad)
            short8 a[4];
            #pragma unroll
            for (int ct = 0; ct < 4; ++ct)
                a[ct] = *(const short8*)(abase +
                    ((size_t)tap * CIB8 * 256 + ct * 16) * 8);

            int tapc = min(tap, 48);
            int kh = tapc / 7, kw = tapc - kh * 7;
            int c = qxl * 4 + kw;
            int pbase = kh * 35 + (c & 3) * 9 + (c >> 2) + pyl * 140;
            #pragma unroll
            for (int pt = 0; pt < 4; ++pt) {
                int posp = pbase + pt * 280;
                short8 b = *(const short8*)&pt3[posp * 12 + ci_half * 4];
                #pragma unroll
                for (int ct = 0; ct < 4; ++ct)
                    acc[ct][pt] = __builtin_amdgcn_mfma_f32_16x16x32_bf16(
                        a[ct], b, acc[ct][pt], 0, 0, 0);
            }
        }
    }

    #pragma unroll
    for (int ct = 0; ct < 4; ++ct) {
        int cobase = wave * 64 + ct * 16 + quad * 4;
        #pragma unroll
        for (int pt = 0; pt < 4; ++pt) {
            int px = pt * 16 + l15;
            int oh = oh0 + (px >> 3), ow = ow0 + (px & 7);
            int pxg = oh * OH + ow;
            #pragma unroll
            for (int r = 0; r < 4; ++r) {
                int co = cobase + r;
                float v = acc[ct][pt][r];
                if (WRITE_T) {
                    float o = fmaxf(bias[co] + v, 0.f);
                    // blocked: [img][co>>4][OH*OH][co&15]
                    outT[(size_t)img * (OH * OH * 256)
                         + ((size_t)(co >> 4) * (OH * OH) + pxg) * 16 + (co & 15)]
                        = __float2bfloat16(o);
                } else {
                    atomicAdd(&outA[(size_t)img * (OH * OH * 256) + (size_t)co * (OH * OH)
                                    + pxg], v);
                }
            }
        }
    }
}

// combine3 -> NHWC bf16 (h3T stays flat NHWC; conv4 stages 32-ci chunks)
__global__ void combine3_k(const float* __restrict__ p3, const float* __restrict__ bias,
                           bf16* __restrict__ h3T)
{
    int idx = blockIdx.x * 256 + threadIdx.x;
    int px = idx & 255;
    int co = (idx >> 8) & 255;
    int img = idx >> 16;
    float v = fmaxf(bias[co] + p3[idx], 0.f);
    h3T[((size_t)img * 256 + px) * 256 + co] = __float2bfloat16(v);
}

// ===========================================================================
// conv4 MFMA: 3x3 s2 p1, 256->256 ch, 16->8, NHWC bf16, relu. grid 8.
// ===========================================================================
__global__ __launch_bounds__(256) void conv4m_k(const bf16* __restrict__ h3T,
        const bf16* __restrict__ wp4, const float* __restrict__ bias,
        bf16* __restrict__ h4T)
{
    int img = blockIdx.x;
    int t = threadIdx.x;
    int wave = t >> 6, lane = t & 63;
    int quad = lane >> 4, l15 = lane & 15;

    __shared__ uint pt[16 * 325];

    for (int i = t; i < 16 * 325; i += 256) pt[i] = 0;

    f32x4 zero = {0.f, 0.f, 0.f, 0.f};
    f32x4 acc[4][4];
    #pragma unroll
    for (int a = 0; a < 4; ++a)
        #pragma unroll
        for (int b = 0; b < 4; ++b) acc[a][b] = zero;

    const bf16* inb = h3T + (size_t)img * 65536;

    for (int ch = 0; ch < 8; ++ch) {
        __syncthreads();
        for (int e = t; e < 4096; e += 256) {
            int cp = e & 15, px = e >> 4;
            int py = px >> 4, qx = px & 15;
            uint v = *(const uint*)(inb + (size_t)px * 256 + ch * 32 + cp * 2);
            pt[cp * 325 + (py + 1) * 18 + qx + 1] = v;
        }
        __syncthreads();

        for (int tap = 0; tap < 9; ++tap) {
            int kh = tap / 3, kw = tap - kh * 3;
            const bf16* abase = wp4 + ((size_t)((tap * 32 + ch * 4 + quad) * 256)
                                       + wave * 64 + l15) * 8;
            short8 a[4];
            #pragma unroll
            for (int ct = 0; ct < 4; ++ct)
                a[ct] = *(const short8*)(abase + ct * 16 * 8);
            #pragma unroll
            for (int pq = 0; pq < 4; ++pq) {
                int pyo = 2 * pq + (l15 >> 3);
                int ipos = (2 * pyo + kh) * 18 + 2 * (l15 & 7) + kw;
                union { short8 v; uint u[4]; } b;
                b.u[0] = pt[(quad * 4 + 0) * 325 + ipos];
                b.u[1] = pt[(quad * 4 + 1) * 325 + ipos];
                b.u[2] = pt[(quad * 4 + 2) * 325 + ipos];
                b.u[3] = pt[(quad * 4 + 3) * 325 + ipos];
                #pragma unroll
                for (int ct = 0; ct < 4; ++ct)
                    acc[ct][pq] = __builtin_amdgcn_mfma_f32_16x16x32_bf16(
                        a[ct], b.v, acc[ct][pq], 0, 0, 0);
            }
        }
    }

    #pragma unroll
    for (int ct = 0; ct < 4; ++ct) {
        int cobase = wave * 64 + ct * 16 + quad * 4;
        #pragma unroll
        for (int pq = 0; pq < 4; ++pq) {
            int px = pq * 16 + l15;
            #pragma unroll
            for (int r = 0; r < 4; ++r) {
                int co = cobase + r;
                float v = fmaxf(bias[co] + acc[ct][pq][r], 0.f);
                h4T[((size_t)img * 64 + px) * 256 + co] = __float2bfloat16(v);
            }
        }
    }
}

// ===========================================================================
// res-a MFMA: t1 = conv1x3(relu(h)), 256->1024. grid 32.
// ===========================================================================
__global__ __launch_bounds__(256) void resam_k(const bf16* __restrict__ hT,
        const bf16* __restrict__ wpA, bf16* __restrict__ t1T)
{
    int bid = blockIdx.x;
    int img = bid >> 2, g = bid & 3;
    int t = threadIdx.x;
    int wave = t >> 6, lane = t & 63;
    int quad = lane >> 4, l15 = lane & 15;

    __shared__ uint ph[128 * 81];

    for (int i = t; i < 128 * 81; i += 256) ph[i] = 0;
    __syncthreads();
    const bf16* inb = hT + (size_t)img * 16384;
    for (int e = t; e < 8192; e += 256) {
        int cp = e & 127, px = e >> 7;
        uint v = relu2(*(const uint*)(inb + (size_t)px * 256 + cp * 2));
        ph[cp * 81 + (px >> 3) * 10 + (px & 7) + 1] = v;
    }
    __syncthreads();

    f32x4 zero = {0.f, 0.f, 0.f, 0.f};
    f32x4 acc[4][4];
    #pragma unroll
    for (int a = 0; a < 4; ++a)
        #pragma unroll
        for (int b = 0; b < 4; ++b) acc[a][b] = zero;

    for (int ch = 0; ch < 8; ++ch) {
        for (int tap = 0; tap < 3; ++tap) {
            const bf16* abase = wpA + ((size_t)(tap * 32 + ch * 4 + quad) * 1024
                                       + g * 256 + wave * 64 + l15) * 8;
            short8 a[4];
            #pragma unroll
            for (int ct = 0; ct < 4; ++ct)
                a[ct] = *(const short8*)(abase + ct * 16 * 8);
            #pragma unroll
            for (int pq = 0; pq < 4; ++pq) {
                int py = 2 * pq + (l15 >> 3);
                int pos = py * 10 + (l15 & 7) + tap;
                union { short8 v; uint u[4]; } b;
                b.u[0] = ph[(ch * 16 + quad * 4 + 0) * 81 + pos];
                b.u[1] = ph[(ch * 16 + quad * 4 + 1) * 81 + pos];
                b.u[2] = ph[(ch * 16 + quad * 4 + 2) * 81 + pos];
                b.u[3] = ph[(ch * 16 + quad * 4 + 3) * 81 + pos];
                #pragma unroll
                for (int ct = 0; ct < 4; ++ct)
                    acc[ct][pq] = __builtin_amdgcn_mfma_f32_16x16x32_bf16(
                        a[ct], b.v, acc[ct][pq], 0, 0, 0);
            }
        }
    }

    #pragma unroll
    for (int ct = 0; ct < 4; ++ct) {
        int cobase = g * 256 + wave * 64 + ct * 16 + quad * 4;
        #pragma unroll
        for (int pq = 0; pq < 4; ++pq) {
            int px = pq * 16 + l15;
            #pragma unroll
            for (int r = 0; r < 4; ++r)
                t1T[((size_t)img * 64 + px) * 1024 + cobase + r]
                    = __float2bfloat16(acc[ct][pq][r]);
        }
    }
}

// ===========================================================================
// res-b MFMA: h_new = h_old + conv1x1(relu(t1)), 1024->256. grid 8.
// ===========================================================================
__global__ __launch_bounds__(256) void resbm_k(const bf16* __restrict__ holdT,
        const bf16* __restrict__ t1T, const bf16* __restrict__ wpB,
        bf16* __restrict__ hnewT)
{
    int img = blockIdx.x;
    int t = threadIdx.x;
    int wave = t >> 6, lane = t & 63;
    int quad = lane >> 4, l15 = lane & 15;

    __shared__ uint pb[256 * 65];

    f32x4 zero = {0.f, 0.f, 0.f, 0.f};
    f32x4 acc[4][4];
    #pragma unroll
    for (int a = 0; a < 4; ++a)
        #pragma unroll
        for (int b = 0; b < 4; ++b) acc[a][b] = zero;

    const bf16* inb = t1T + (size_t)img * 65536;

    for (int s = 0; s < 2; ++s) {
        __syncthreads();
        for (int e = t; e < 16384; e += 256) {
            int cp = e & 255, px = e >> 8;
            uint v = relu2(*(const uint*)(inb + (size_t)px * 1024 + s * 512 + cp * 2));
            pb[cp * 65 + px] = v;
        }
        __syncthreads();

        for (int chl = 0; chl < 16; ++chl) {
            int ch = s * 16 + chl;
            const bf16* abase = wpB + ((size_t)(ch * 4 + quad) * 256
                                       + wave * 64 + l15) * 8;
            short8 a[4];
            #pragma unroll
            for (int ct = 0; ct < 4; ++ct)
                a[ct] = *(const short8*)(abase + ct * 16 * 8);
            #pragma unroll
            for (int pq = 0; pq < 4; ++pq) {
                int px = pq * 16 + l15;
                union { short8 v; uint u[4]; } b;
                b.u[0] = pb[(chl * 16 + quad * 4 + 0) * 65 + px];
                b.u[1] = pb[(chl * 16 + quad * 4 + 1) * 65 + px];
                b.u[2] = pb[(chl * 16 + quad * 4 + 2) * 65 + px];
                b.u[3] = pb[(chl * 16 + quad * 4 + 3) * 65 + px];
                #pragma unroll
                for (int ct = 0; ct < 4; ++ct)
                    acc[ct][pq] = __builtin_amdgcn_mfma_f32_16x16x32_bf16(
                        a[ct], b.v, acc[ct][pq], 0, 0, 0);
            }
        }
    }

    #pragma unroll
    for (int ct = 0; ct < 4; ++ct) {
        int cobase = wave * 64 + ct * 16 + quad * 4;
        #pragma unroll
        for (int pq = 0; pq < 4; ++pq) {
            int px = pq * 16 + l15;
            #pragma unroll
            for (int r = 0; r < 4; ++r) {
                int co = cobase + r;
                size_t o = ((size_t)img * 64 + px) * 256 + co;
                float v = b2f(holdT[o]) + acc[ct][pq][r];
                hnewT[o] = __float2bfloat16(v);
            }
        }
    }
}

__global__ void embnorm_k(const float* __restrict__ emb, float* __restrict__ en)
{
    int k = blockIdx.x * 256 + threadIdx.x;
    const float* e = emb + (size_t)k * 256;
    float s = 0.f;
    for (int d = 0; d < 256; ++d) { float v = e[d]; s += v * v; }
    en[k] = s;
}

// VQ: one block per latent row (512). Reads h6T NHWC bf16 (relu'd here).
__global__ void vq_k(const bf16* __restrict__ h6T, const float* __restrict__ emb,
                     const float* __restrict__ en, float* __restrict__ out,
                     float* __restrict__ mse_acc, int* __restrict__ hist)
{
    int row = blockIdx.x;
    int b = row >> 6, y = (row >> 3) & 7, xx = row & 7;
    int t = threadIdx.x;
    __shared__ float lat[256];
    __shared__ float sdist[256];
    __shared__ int   sidx[256];

    float l = fmaxf(b2f(h6T[(size_t)row * 256 + t]), 0.f);
    lat[t] = l;
    __syncthreads();

    float d0 = 0.f, d1 = 0.f;
    const float* e0 = emb + (size_t)t * 256;
    const float* e1 = emb + (size_t)(t + 256) * 256;
    for (int d = 0; d < 256; ++d) {
        float lv = lat[d];
        d0 += lv * e0[d];
        d1 += lv * e1[d];
    }
    d0 = en[t] - 2.f * d0;
    d1 = en[t + 256] - 2.f * d1;
    float best_d = d0; int best_i = t;
    if (d1 < best_d) { best_d = d1; best_i = t + 256; }
    sdist[t] = best_d; sidx[t] = best_i;
    __syncthreads();
    for (int s = 128; s > 0; s >>= 1) {
        if (t < s) {
            float od = sdist[t + s]; int oi = sidx[t + s];
            if (od < sdist[t] || (od == sdist[t] && oi < sidx[t])) {
                sdist[t] = od; sidx[t] = oi;
            }
        }
        __syncthreads();
    }
    int idx = sidx[0];

    float q = emb[(size_t)idx * 256 + t];
    out[((size_t)(b * 256 + t) * 8 + y) * 8 + xx] = q;
    float diff = q - lat[t];
    __syncthreads();
    sdist[t] = diff * diff;
    __syncthreads();
    for (int s = 128; s > 0; s >>= 1) {
        if (t < s) sdist[t] += sdist[t + s];
        __syncthreads();
    }
    if (t == 0) {
        atomicAdd(mse_acc, sdist[0]);
        atomicAdd(&hist[idx], 1);
    }
}

__global__ void final_k(const float* __restrict__ mse_acc, const int* __restrict__ hist,
                        float* __restrict__ out)
{
    __shared__ float sh[512];
    int t = threadIdx.x;
    float p = (float)hist[t] / 512.f;
    sh[t] = p * logf(p + 1e-10f);
    __syncthreads();
    for (int s = 256; s > 0; s >>= 1) {
        if (t < s) sh[t] += sh[t + s];
        __syncthreads();
    }
    if (t == 0) {
        float loss = 2.f * mse_acc[0] / (512.f * 256.f);
        float perp = expf(-sh[0]);
        out[131072] = loss;
        out[131073] = perp;
    }
}

// ===========================================================================
extern "C" void kernel_launch(void* const* d_in, const int* in_sizes, int n_in,
                              void* d_out, int out_size, void* d_ws, size_t ws_size,
                              hipStream_t stream)
{
    const float* x    = (const float*)d_in[0];
    const float* w_in = (const float*)d_in[1];
    const float* b_in = (const float*)d_in[2];
    const float* w_h1 = (const float*)d_in[3];
    const float* b_h1 = (const float*)d_in[4];
    const float* w_h2 = (const float*)d_in[5];
    const float* b_h2 = (const float*)d_in[6];
    const float* w_h3 = (const float*)d_in[7];
    const float* b_h3 = (const float*)d_in[8];
    const float* r0w1 = (const float*)d_in[9];
    const float* r0w2 = (const float*)d_in[10];
    const float* r1w1 = (const float*)d_in[11];
    const float* r1w2 = (const float*)d_in[12];
    const float* emb  = (const float*)d_in[13];
    float* out = (float*)d_out;

    char* ws = (char*)d_ws;
    size_t off = 0;
    auto alloc = [&](size_t bytes) -> void* {
        void* p = ws + off;
        off += (bytes + 255) & ~(size_t)255;
        return p;
    };

    float* en  = (float*)alloc(512 * 4);
    float* mse = (float*)alloc(256);
    int*  hist = (int*)alloc(512 * 4);
    float* p3  = (float*)alloc(524288ull * 4);
    bf16* h3T  = (bf16*)alloc(524288ull * 2);
    bf16* h4T  = (bf16*)alloc(131072ull * 2);
    bf16* t1T  = (bf16*)alloc(524288ull * 2);
    bf16* h5T  = (bf16*)alloc(131072ull * 2);
    bf16* h6T  = (bf16*)alloc(131072ull * 2);
    bf16* wp1  = (bf16*)alloc(8192ull * 2);
    bf16* wpack2 = (bf16*)alloc(1638400ull * 2);
    bf16* wpack3 = (bf16*)alloc(3276800ull * 2);
    bf16* wp4  = (bf16*)alloc(589824ull * 2);
    bf16* wpA0 = (bf16*)alloc(786432ull * 2);
    bf16* wpA1 = (bf16*)alloc(786432ull * 2);
    bf16* wpB0 = (bf16*)alloc(262144ull * 2);
    bf16* wpB1 = (bf16*)alloc(262144ull * 2);
    bf16* h2c  = (bf16*)alloc(8388608ull * 2);     // [8][16 blk][4096 px][16]
    size_t base_end = off;

    const size_t H1TI = 8388608;
    size_t needFull = base_end + H1TI * 8 * 2 + 4096;
    bool full = ws_size >= needFull;
    bf16* h1c = (bf16*)alloc(full ? H1TI * 8 * 2 : H1TI * 2);

    hipMemsetAsync(mse, 0, 4, stream);
    hipMemsetAsync(hist, 0, 512 * 4, stream);
    hipMemsetAsync(p3, 0, 524288ull * 4, stream);

    wpack1_k<<<32, 256, 0, stream>>>(w_in, wp1);
    wpack_k<128><<<6400, 256, 0, stream>>>(w_h1, wpack2);
    wpack_k<256><<<12800, 256, 0, stream>>>(w_h2, wpack3);
    wpack_g<9, 256, 32><<<2304, 256, 0, stream>>>(w_h3, wp4);
    wpack_g<3, 1024, 32><<<3072, 256, 0, stream>>>(r0w1, wpA0);
    wpack_g<3, 1024, 32><<<3072, 256, 0, stream>>>(r1w1, wpA1);
    wpack_g<1, 256, 128><<<1024, 256, 0, stream>>>(r0w2, wpB0);
    wpack_g<1, 256, 128><<<1024, 256, 0, stream>>>(r1w2, wpB1);

    if (full) {
        conv1m_k<<<4096, 256, 0, stream>>>(x, wp1, b_in, h1c);
        conv_mfma4_k<256, 64, 128, 1, true><<<512, 256, 0, stream>>>(
            h1c, wpack2, b_h1, nullptr, h2c);
    } else {
        for (int n = 0; n < 8; ++n) {
            conv1m_k<<<512, 256, 0, stream>>>(x + (size_t)n * 786432, wp1, b_in, h1c);
            conv_mfma4_k<256, 64, 128, 1, true><<<64, 256, 0, stream>>>(
                h1c, wpack2, b_h1, nullptr, h2c + (size_t)n * 1048576);
        }
    }

    conv_mfma4_k<64, 16, 256, 8, false><<<256, 256, 0, stream>>>(
        h2c, wpack3, b_h2, p3, nullptr);
    combine3_k<<<2048, 256, 0, stream>>>(p3, b_h2, h3T);

    conv4m_k<<<8, 256, 0, stream>>>(h3T, wp4, b_h3, h4T);
    resam_k<<<32, 256, 0, stream>>>(h4T, wpA0, t1T);
    resbm_k<<<8, 256, 0, stream>>>(h4T, t1T, wpB0, h5T);
    resam_k<<<32, 256, 0, stream>>>(h5T, wpA1, t1T);
    resbm_k<<<8, 256, 0, stream>>>(h5T, t1T, wpB1, h6T);

    embnorm_k<<<2, 256, 0, stream>>>(emb, en);
    vq_k<<<512, 256, 0, stream>>>(h6T, emb, en, out, mse, hist);
    final_k<<<1, 512, 0, stream>>>(mse, hist, out);
}

// Round 13
// 587.949 us; speedup vs baseline: 1.1003x; 1.0085x over previous
//
#include <hip/hip_runtime.h>
#include <hip/hip_bf16.h>

typedef __hip_bfloat16 bf16;
typedef __attribute__((ext_vector_type(4))) float f32x4;
typedef __attribute__((ext_vector_type(8))) short short8;

__device__ __forceinline__ float b2f(bf16 v) { return __bfloat162float(v); }
__device__ __forceinline__ ushort f2bu(float v)
{
    bf16 b = __float2bfloat16(v);
    return *(ushort*)&b;
}
__device__ __forceinline__ uint relu2(uint v)
{
    uint r = v;
    if (r & 0x8000u)     r &= 0xFFFF0000u;
    if (r & 0x80000000u) r &= 0x0000FFFFu;
    return r;
}
__device__ __forceinline__ uint packbf2(float a, float b)
{
    uint lo = f2bu(a), hi = f2bu(b);
    return lo | (hi << 16);
}

// ===========================================================================
// init_k: ALL weight packs + emb norms + zero(mse,hist,p3) in ONE kernel
// (was 9 kernels + 3 memsets -> saves ~11 launch gaps).
// Ranges (in order): wp1 8192 | wpack2 1,638,400 | wpack3 3,276,800 |
// wp4 589,824 | wpA0/wpA1 786,432 ea | wpB0/wpB1 262,144 ea | en 512 |
// misc 513 | p3 524,288.  Total 8,135,681 -> grid 31781.
// ===========================================================================
__global__ void init_k(const float* __restrict__ w_in, const float* __restrict__ w_h1,
        const float* __restrict__ w_h2, const float* __restrict__ w_h3,
        const float* __restrict__ r0w1, const float* __restrict__ r0w2,
        const float* __restrict__ r1w1, const float* __restrict__ r1w2,
        const float* __restrict__ emb,
        bf16* __restrict__ wp1, bf16* __restrict__ wpack2, bf16* __restrict__ wpack3,
        bf16* __restrict__ wp4, bf16* __restrict__ wpA0, bf16* __restrict__ wpA1,
        bf16* __restrict__ wpB0, bf16* __restrict__ wpB1,
        float* __restrict__ en, float* __restrict__ mse, int* __restrict__ hist,
        float* __restrict__ p3)
{
    long long i = (long long)blockIdx.x * 256 + threadIdx.x;
    if (i < 8192) {                                        // wp1
        int j = i & 7; int co = (i >> 3) & 127; int kb = i >> 10;
        int k = kb * 8 + j;
        wp1[i] = __float2bfloat16(k < 48 ? w_in[co * 48 + k] : 0.f);
        return;
    }
    i -= 8192;
    if (i < 1638400) {                                     // wpack2 CI=128
        int cil = i & 7; int co = (i >> 3) & 255; int r = i >> 11;
        int cib8 = r % 16; int tap = r / 16;
        float v = (tap < 49) ? w_h1[(size_t)co * 6272 + (cib8 * 8 + cil) * 49 + tap] : 0.f;
        wpack2[i] = __float2bfloat16(v);
        return;
    }
    i -= 1638400;
    if (i < 3276800) {                                     // wpack3 CI=256
        int cil = i & 7; int co = (i >> 3) & 255; int r = i >> 11;
        int cib8 = r % 32; int tap = r / 32;
        float v = (tap < 49) ? w_h2[(size_t)co * 12544 + (cib8 * 8 + cil) * 49 + tap] : 0.f;
        wpack3[i] = __float2bfloat16(v);
        return;
    }
    i -= 3276800;
    if (i < 589824) {                                      // wp4 KT=9 CIB8=32
        int cil = i & 7; int co = (i >> 3) & 255; int r = i >> 11;
        int cib8 = r % 32; int tap = r / 32;
        wp4[i] = __float2bfloat16(w_h3[(size_t)co * 2304 + (cib8 * 8 + cil) * 9 + tap]);
        return;
    }
    i -= 589824;
    if (i < 786432) {                                      // wpA0 KT=3 CO=1024
        int cil = i & 7; int co = (i >> 3) & 1023; int r = i >> 13;
        int cib8 = r % 32; int tap = r / 32;
        wpA0[i] = __float2bfloat16(r0w1[(size_t)co * 768 + (cib8 * 8 + cil) * 3 + tap]);
        return;
    }
    i -= 786432;
    if (i < 786432) {                                      // wpA1
        int cil = i & 7; int co = (i >> 3) & 1023; int r = i >> 13;
        int cib8 = r % 32; int tap = r / 32;
        wpA1[i] = __float2bfloat16(r1w1[(size_t)co * 768 + (cib8 * 8 + cil) * 3 + tap]);
        return;
    }
    i -= 786432;
    if (i < 262144) {                                      // wpB0 KT=1 CIB8=128
        int cil = i & 7; int co = (i >> 3) & 255; int cib8 = (i >> 11) % 128;
        wpB0[i] = __float2bfloat16(r0w2[(size_t)co * 1024 + cib8 * 8 + cil]);
        return;
    }
    i -= 262144;
    if (i < 262144) {                                      // wpB1
        int cil = i & 7; int co = (i >> 3) & 255; int cib8 = (i >> 11) % 128;
        wpB1[i] = __float2bfloat16(r1w2[(size_t)co * 1024 + cib8 * 8 + cil]);
        return;
    }
    i -= 262144;
    if (i < 512) {                                         // emb norms
        const float* e = emb + (size_t)i * 256;
        float s = 0.f;
        for (int d = 0; d < 256; ++d) { float v = e[d]; s += v * v; }
        en[i] = s;
        return;
    }
    i -= 512;
    if (i < 513) {                                         // zero mse + hist
        if (i == 0) mse[0] = 0.f;
        else hist[i - 1] = 0;
        return;
    }
    i -= 513;
    if (i < 524288) p3[i] = 0.f;                           // zero conv3 partials
}

// ===========================================================================
// conv1 MFMA -> ci-BLOCKED bf16 h1c[img][ci16][px][16]. Unchanged (R12 pass).
// ===========================================================================
__global__ __launch_bounds__(256) void conv1m_k(const float* __restrict__ x,
        const bf16* __restrict__ wp1, const float* __restrict__ bias,
        bf16* __restrict__ h1c)
{
    int bid = blockIdx.x;
    int pxt = bid & 511, img = bid >> 9;
    int tr = pxt >> 4, tc = pxt & 15;
    int oh0 = tr * 8, ow0 = tc * 16;
    const float* xi = x + (size_t)img * 786432;
    bf16* oT = h1c + (size_t)img * 8388608;

    int t = threadIdx.x;
    int wave = t >> 6, lane = t & 63;
    int quad = lane >> 4, l15 = lane & 15;

    __shared__ ushort xs[4 * 640];
    __shared__ ushort ot[128 * 136];

    int ihb = oh0 * 2 - 1, iwb = ow0 * 2 - 1;
    for (int i = t; i < 1836; i += 256) {
        int ci = i / 612; int r1 = i - ci * 612;
        int ihl = r1 / 34, iwl = r1 - ihl * 34;
        int ih = ihb + ihl, iw = iwb + iwl;
        float v = 0.f;
        if ((unsigned)ih < 512u && (unsigned)iw < 512u)
            v = xi[ci * 262144 + ih * 512 + iw];
        xs[ci * 640 + ihl * 35 + iwl] = f2bu(v);
    }
    for (int i = t; i < 640; i += 256) xs[3 * 640 + i] = 0;
    __syncthreads();

    f32x4 zero = {0.f, 0.f, 0.f, 0.f};
    f32x4 acc[8][2];
    #pragma unroll
    for (int m = 0; m < 8; ++m) { acc[m][0] = zero; acc[m][1] = zero; }

    int ci_b = quad >> 1;
    int kh0 = (quad & 1) * 2;
    int iwl0 = 2 * l15;

    #pragma unroll
    for (int ks = 0; ks < 2; ++ks) {
        union { short8 v; uint u[4]; } b[2];
        #pragma unroll
        for (int nt = 0; nt < 2; ++nt) {
            int py = wave * 2 + nt;
            int base = (ks * 2 + ci_b) * 640 + (2 * py + kh0) * 35 + iwl0;
            b[nt].u[0] = *(const uint*)&xs[base];
            b[nt].u[1] = *(const uint*)&xs[base + 2];
            b[nt].u[2] = *(const uint*)&xs[base + 35];
            b[nt].u[3] = *(const uint*)&xs[base + 37];
        }
        const bf16* abase = wp1 + ((size_t)(ks * 4 + quad) * 128 + l15) * 8;
        #pragma unroll
        for (int m = 0; m < 8; ++m) {
            short8 a = *(const short8*)(abase + m * 16 * 8);
            acc[m][0] = __builtin_amdgcn_mfma_f32_16x16x32_bf16(a, b[0].v, acc[m][0], 0, 0, 0);
            acc[m][1] = __builtin_amdgcn_mfma_f32_16x16x32_bf16(a, b[1].v, acc[m][1], 0, 0, 0);
        }
    }

    #pragma unroll
    for (int m = 0; m < 8; ++m) {
        int cobase = m * 16 + quad * 4;
        float b0 = bias[cobase], b1 = bias[cobase + 1];
        float b2 = bias[cobase + 2], b3 = bias[cobase + 3];
        #pragma unroll
        for (int nt = 0; nt < 2; ++nt) {
            int pxl = (wave * 2 + nt) * 16 + l15;
            uint w0 = packbf2(fmaxf(b0 + acc[m][nt][0], 0.f),
                              fmaxf(b1 + acc[m][nt][1], 0.f));
            uint w1 = packbf2(fmaxf(b2 + acc[m][nt][2], 0.f),
                              fmaxf(b3 + acc[m][nt][3], 0.f));
            *(uint*)&ot[pxl * 136 + cobase]     = w0;
            *(uint*)&ot[pxl * 136 + cobase + 2] = w1;
        }
    }
    __syncthreads();
    {
        int pxl = t >> 1, half = t & 1;
        int oh = oh0 + (pxl >> 4), ow = ow0 + (pxl & 15);
        size_t px = (size_t)(oh * 256 + ow);
        #pragma unroll
        for (int cb = 0; cb < 4; ++cb) {
            int c16 = half * 4 + cb;
            const uint4* src = (const uint4*)&ot[pxl * 136 + c16 * 16];
            uint4* dst = (uint4*)(oT + ((size_t)c16 * 65536 + px) * 16);
            dst[0] = src[0];
            dst[1] = src[1];
        }
    }
}

// ===========================================================================
// implicit-GEMM MFMA 7x7 s4 p2 conv, v5: v4 + (a) LDS shrunk 58.8->39.2 KB
// via [half][1225][4] layout (bank start 4*posp mod 32 -> 8 distinct starts,
// qxl/pyl <=2-way); (b) MODE: 0 = fused bias+relu -> blocked bf16,
// 1 = f32 atomic partials (NCHW), 2 = raw bf16 slice [split][img][blocked].
// conv2: SPLIT=2 MODE=2, grid 1024 -> 4 blocks/CU (16 waves) so the
// matrix / A-L2 / LDS pipes overlap instead of serializing.
// conv3: SPLIT=8 MODE=1, unchanged semantics.
// ===========================================================================
template <int IH, int OH, int CI, int SPLIT, int MODE>
__global__ __launch_bounds__(256) void conv_mfma5_k(
        const bf16* __restrict__ inC, const bf16* __restrict__ wpack,
        const float* __restrict__ bias, float* __restrict__ outA,
        bf16* __restrict__ outT)
{
    constexpr int TPD = OH / 8;
    constexpr int NT = TPD * TPD;
    constexpr int CPB = (CI / 16) / SPLIT;
    constexpr int CIB8 = CI / 8;
    constexpr int NPX = IH * IH;

    int bid = blockIdx.x;
    int pxt = bid % NT;
    int rest = bid / NT;
    int img = rest & 7;
    int split = rest >> 3;
    int oh0 = (pxt / TPD) * 8, ow0 = (pxt % TPD) * 8;

    int t = threadIdx.x;
    int wave = t >> 6, lane = t & 63;
    int quad = lane >> 4, l15 = lane & 15;

    const bf16* inb = inC + (size_t)img * ((size_t)NPX * CI);

    __shared__ __align__(16) uint pt3[2 * 4900];   // [half][1225][4] = 39.2 KB

    f32x4 zero = {0.f, 0.f, 0.f, 0.f};
    f32x4 acc[4][4];
    #pragma unroll
    for (int a = 0; a < 4; ++a)
        #pragma unroll
        for (int b = 0; b < 4; ++b) acc[a][b] = zero;

    int ihb = oh0 * 4 - 2, iwb = ow0 * 4 - 2;
    int qxl = l15 & 7, pyl = l15 >> 3;
    int tap_par = quad >> 1, ci_half = quad & 1;

    for (int cc = 0; cc < CPB; ++cc) {
        int ch = split * CPB + cc;
        __syncthreads();
        for (int i = t; i < 2450; i += 256) {
            int pos = i >> 1, half = i & 1;
            int r = pos / 35, c = pos - r * 35;
            int ih = ihb + r, iw = iwb + c;
            uint4 v = make_uint4(0u, 0u, 0u, 0u);
            if ((unsigned)ih < (unsigned)IH && (unsigned)iw < (unsigned)IH)
                v = *(const uint4*)(inb + ((size_t)ch * NPX + ih * IH + iw) * 16 + half * 8);
            int posp = r * 35 + (c & 3) * 9 + (c >> 2);
            *(uint4*)&pt3[half * 4900 + posp * 4] = v;
        }
        __syncthreads();

        const bf16* abase = wpack +
            ((size_t)(ch * 2 + ci_half) * 256 + wave * 64 + l15) * 8;
        for (int tp = 0; tp < 25; ++tp) {
            int tap = 2 * tp + tap_par;            // tap 49: A = 0 (pad)
            short8 a[4];
            #pragma unroll
            for (int ct = 0; ct < 4; ++ct)
                a[ct] = *(const short8*)(abase +
                    ((size_t)tap * CIB8 * 256 + ct * 16) * 8);

            int tapc = min(tap, 48);
            int kh = tapc / 7, kw = tapc - kh * 7;
            int c = qxl * 4 + kw;
            int pbase = kh * 35 + (c & 3) * 9 + (c >> 2) + pyl * 140;
            #pragma unroll
            for (int pt = 0; pt < 4; ++pt) {
                int posp = pbase + pt * 280;
                short8 b = *(const short8*)&pt3[ci_half * 4900 + posp * 4];
                #pragma unroll
                for (int ct = 0; ct < 4; ++ct)
                    acc[ct][pt] = __builtin_amdgcn_mfma_f32_16x16x32_bf16(
                        a[ct], b, acc[ct][pt], 0, 0, 0);
            }
        }
    }

    #pragma unroll
    for (int ct = 0; ct < 4; ++ct) {
        int cobase = wave * 64 + ct * 16 + quad * 4;
        #pragma unroll
        for (int pt = 0; pt < 4; ++pt) {
            int px = pt * 16 + l15;
            int oh = oh0 + (px >> 3), ow = ow0 + (px & 7);
            int pxg = oh * OH + ow;
            #pragma unroll
            for (int r = 0; r < 4; ++r) {
                int co = cobase + r;
                float v = acc[ct][pt][r];
                if (MODE == 1) {
                    atomicAdd(&outA[(size_t)img * (OH * OH * 256)
                                    + (size_t)co * (OH * OH) + pxg], v);
                } else {
                    float o = (MODE == 0) ? fmaxf(bias[co] + v, 0.f) : v;
                    size_t base = (size_t)((MODE == 2 ? split * 8 : 0) + img)
                                  * (size_t)(OH * OH * 256);
                    outT[base + ((size_t)(co >> 4) * (OH * OH) + pxg) * 16 + (co & 15)]
                        = __float2bfloat16(o);
                }
            }
        }
    }
}

// combine2: h2c = relu(bias + slice0 + slice1), blocked bf16. grid 32768.
__global__ void combine2_k(const bf16* __restrict__ p2s, const float* __restrict__ bias,
                           bf16* __restrict__ h2c)
{
    int idx = blockIdx.x * 256 + threadIdx.x;      // 8,388,608
    int rem = idx & 1048575;
    int co = ((rem >> 16) << 4) | (idx & 15);
    float v = b2f(p2s[idx]) + b2f(p2s[8388608 + idx]);
    h2c[idx] = __float2bfloat16(fmaxf(bias[co] + v, 0.f));
}

// combine3 -> NHWC bf16
__global__ void combine3_k(const float* __restrict__ p3, const float* __restrict__ bias,
                           bf16* __restrict__ h3T)
{
    int idx = blockIdx.x * 256 + threadIdx.x;
    int px = idx & 255;
    int co = (idx >> 8) & 255;
    int img = idx >> 16;
    float v = fmaxf(bias[co] + p3[idx], 0.f);
    h3T[((size_t)img * 256 + px) * 256 + co] = __float2bfloat16(v);
}

// ===========================================================================
// conv4 MFMA: 3x3 s2 p1, 256->256 ch, 16->8, NHWC bf16, relu. grid 8.
// ===========================================================================
__global__ __launch_bounds__(256) void conv4m_k(const bf16* __restrict__ h3T,
        const bf16* __restrict__ wp4, const float* __restrict__ bias,
        bf16* __restrict__ h4T)
{
    int img = blockIdx.x;
    int t = threadIdx.x;
    int wave = t >> 6, lane = t & 63;
    int quad = lane >> 4, l15 = lane & 15;

    __shared__ uint pt[16 * 325];

    for (int i = t; i < 16 * 325; i += 256) pt[i] = 0;

    f32x4 zero = {0.f, 0.f, 0.f, 0.f};
    f32x4 acc[4][4];
    #pragma unroll
    for (int a = 0; a < 4; ++a)
        #pragma unroll
        for (int b = 0; b < 4; ++b) acc[a][b] = zero;

    const bf16* inb = h3T + (size_t)img * 65536;

    for (int ch = 0; ch < 8; ++ch) {
        __syncthreads();
        for (int e = t; e < 4096; e += 256) {
            int cp = e & 15, px = e >> 4;
            int py = px >> 4, qx = px & 15;
            uint v = *(const uint*)(inb + (size_t)px * 256 + ch * 32 + cp * 2);
            pt[cp * 325 + (py + 1) * 18 + qx + 1] = v;
        }
        __syncthreads();

        for (int tap = 0; tap < 9; ++tap) {
            int kh = tap / 3, kw = tap - kh * 3;
            const bf16* abase = wp4 + ((size_t)((tap * 32 + ch * 4 + quad) * 256)
                                       + wave * 64 + l15) * 8;
            short8 a[4];
            #pragma unroll
            for (int ct = 0; ct < 4; ++ct)
                a[ct] = *(const short8*)(abase + ct * 16 * 8);
            #pragma unroll
            for (int pq = 0; pq < 4; ++pq) {
                int pyo = 2 * pq + (l15 >> 3);
                int ipos = (2 * pyo + kh) * 18 + 2 * (l15 & 7) + kw;
                union { short8 v; uint u[4]; } b;
                b.u[0] = pt[(quad * 4 + 0) * 325 + ipos];
                b.u[1] = pt[(quad * 4 + 1) * 325 + ipos];
                b.u[2] = pt[(quad * 4 + 2) * 325 + ipos];
                b.u[3] = pt[(quad * 4 + 3) * 325 + ipos];
                #pragma unroll
                for (int ct = 0; ct < 4; ++ct)
                    acc[ct][pq] = __builtin_amdgcn_mfma_f32_16x16x32_bf16(
                        a[ct], b.v, acc[ct][pq], 0, 0, 0);
            }
        }
    }

    #pragma unroll
    for (int ct = 0; ct < 4; ++ct) {
        int cobase = wave * 64 + ct * 16 + quad * 4;
        #pragma unroll
        for (int pq = 0; pq < 4; ++pq) {
            int px = pq * 16 + l15;
            #pragma unroll
            for (int r = 0; r < 4; ++r) {
                int co = cobase + r;
                float v = fmaxf(bias[co] + acc[ct][pq][r], 0.f);
                h4T[((size_t)img * 64 + px) * 256 + co] = __float2bfloat16(v);
            }
        }
    }
}

// ===========================================================================
// res-a MFMA: t1 = conv1x3(relu(h)), 256->1024. grid 32.
// ===========================================================================
__global__ __launch_bounds__(256) void resam_k(const bf16* __restrict__ hT,
        const bf16* __restrict__ wpA, bf16* __restrict__ t1T)
{
    int bid = blockIdx.x;
    int img = bid >> 2, g = bid & 3;
    int t = threadIdx.x;
    int wave = t >> 6, lane = t & 63;
    int quad = lane >> 4, l15 = lane & 15;

    __shared__ uint ph[128 * 81];

    for (int i = t; i < 128 * 81; i += 256) ph[i] = 0;
    __syncthreads();
    const bf16* inb = hT + (size_t)img * 16384;
    for (int e = t; e < 8192; e += 256) {
        int cp = e & 127, px = e >> 7;
        uint v = relu2(*(const uint*)(inb + (size_t)px * 256 + cp * 2));
        ph[cp * 81 + (px >> 3) * 10 + (px & 7) + 1] = v;
    }
    __syncthreads();

    f32x4 zero = {0.f, 0.f, 0.f, 0.f};
    f32x4 acc[4][4];
    #pragma unroll
    for (int a = 0; a < 4; ++a)
        #pragma unroll
        for (int b = 0; b < 4; ++b) acc[a][b] = zero;

    for (int ch = 0; ch < 8; ++ch) {
        for (int tap = 0; tap < 3; ++tap) {
            const bf16* abase = wpA + ((size_t)(tap * 32 + ch * 4 + quad) * 1024
                                       + g * 256 + wave * 64 + l15) * 8;
            short8 a[4];
            #pragma unroll
            for (int ct = 0; ct < 4; ++ct)
                a[ct] = *(const short8*)(abase + ct * 16 * 8);
            #pragma unroll
            for (int pq = 0; pq < 4; ++pq) {
                int py = 2 * pq + (l15 >> 3);
                int pos = py * 10 + (l15 & 7) + tap;
                union { short8 v; uint u[4]; } b;
                b.u[0] = ph[(ch * 16 + quad * 4 + 0) * 81 + pos];
                b.u[1] = ph[(ch * 16 + quad * 4 + 1) * 81 + pos];
                b.u[2] = ph[(ch * 16 + quad * 4 + 2) * 81 + pos];
                b.u[3] = ph[(ch * 16 + quad * 4 + 3) * 81 + pos];
                #pragma unroll
                for (int ct = 0; ct < 4; ++ct)
                    acc[ct][pq] = __builtin_amdgcn_mfma_f32_16x16x32_bf16(
                        a[ct], b.v, acc[ct][pq], 0, 0, 0);
            }
        }
    }

    #pragma unroll
    for (int ct = 0; ct < 4; ++ct) {
        int cobase = g * 256 + wave * 64 + ct * 16 + quad * 4;
        #pragma unroll
        for (int pq = 0; pq < 4; ++pq) {
            int px = pq * 16 + l15;
            #pragma unroll
            for (int r = 0; r < 4; ++r)
                t1T[((size_t)img * 64 + px) * 1024 + cobase + r]
                    = __float2bfloat16(acc[ct][pq][r]);
        }
    }
}

// ===========================================================================
// res-b MFMA: h_new = h_old + conv1x1(relu(t1)), 1024->256. grid 8.
// ===========================================================================
__global__ __launch_bounds__(256) void resbm_k(const bf16* __restrict__ holdT,
        const bf16* __restrict__ t1T, const bf16* __restrict__ wpB,
        bf16* __restrict__ hnewT)
{
    int img = blockIdx.x;
    int t = threadIdx.x;
    int wave = t >> 6, lane = t & 63;
    int quad = lane >> 4, l15 = lane & 15;

    __shared__ uint pb[256 * 65];

    f32x4 zero = {0.f, 0.f, 0.f, 0.f};
    f32x4 acc[4][4];
    #pragma unroll
    for (int a = 0; a < 4; ++a)
        #pragma unroll
        for (int b = 0; b < 4; ++b) acc[a][b] = zero;

    const bf16* inb = t1T + (size_t)img * 65536;

    for (int s = 0; s < 2; ++s) {
        __syncthreads();
        for (int e = t; e < 16384; e += 256) {
            int cp = e & 255, px = e >> 8;
            uint v = relu2(*(const uint*)(inb + (size_t)px * 1024 + s * 512 + cp * 2));
            pb[cp * 65 + px] = v;
        }
        __syncthreads();

        for (int chl = 0; chl < 16; ++chl) {
            int ch = s * 16 + chl;
            const bf16* abase = wpB + ((size_t)(ch * 4 + quad) * 256
                                       + wave * 64 + l15) * 8;
            short8 a[4];
            #pragma unroll
            for (int ct = 0; ct < 4; ++ct)
                a[ct] = *(const short8*)(abase + ct * 16 * 8);
            #pragma unroll
            for (int pq = 0; pq < 4; ++pq) {
                int px = pq * 16 + l15;
                union { short8 v; uint u[4]; } b;
                b.u[0] = pb[(chl * 16 + quad * 4 + 0) * 65 + px];
                b.u[1] = pb[(chl * 16 + quad * 4 + 1) * 65 + px];
                b.u[2] = pb[(chl * 16 + quad * 4 + 2) * 65 + px];
                b.u[3] = pb[(chl * 16 + quad * 4 + 3) * 65 + px];
                #pragma unroll
                for (int ct = 0; ct < 4; ++ct)
                    acc[ct][pq] = __builtin_amdgcn_mfma_f32_16x16x32_bf16(
                        a[ct], b.v, acc[ct][pq], 0, 0, 0);
            }
        }
    }

    #pragma unroll
    for (int ct = 0; ct < 4; ++ct) {
        int cobase = wave * 64 + ct * 16 + quad * 4;
        #pragma unroll
        for (int pq = 0; pq < 4; ++pq) {
            int px = pq * 16 + l15;
            #pragma unroll
            for (int r = 0; r < 4; ++r) {
                int co = cobase + r;
                size_t o = ((size_t)img * 64 + px) * 256 + co;
                float v = b2f(holdT[o]) + acc[ct][pq][r];
                hnewT[o] = __float2bfloat16(v);
            }
        }
    }
}

// VQ: one block per latent row (512). Reads h6T NHWC bf16 (relu'd here).
__global__ void vq_k(const bf16* __restrict__ h6T, const float* __restrict__ emb,
                     const float* __restrict__ en, float* __restrict__ out,
                     float* __restrict__ mse_acc, int* __restrict__ hist)
{
    int row = blockIdx.x;
    int b = row >> 6, y = (row >> 3) & 7, xx = row & 7;
    int t = threadIdx.x;
    __shared__ float lat[256];
    __shared__ float sdist[256];
    __shared__ int   sidx[256];

    float l = fmaxf(b2f(h6T[(size_t)row * 256 + t]), 0.f);
    lat[t] = l;
    __syncthreads();

    float d0 = 0.f, d1 = 0.f;
    const float* e0 = emb + (size_t)t * 256;
    const float* e1 = emb + (size_t)(t + 256) * 256;
    for (int d = 0; d < 256; ++d) {
        float lv = lat[d];
        d0 += lv * e0[d];
        d1 += lv * e1[d];
    }
    d0 = en[t] - 2.f * d0;
    d1 = en[t + 256] - 2.f * d1;
    float best_d = d0; int best_i = t;
    if (d1 < best_d) { best_d = d1; best_i = t + 256; }
    sdist[t] = best_d; sidx[t] = best_i;
    __syncthreads();
    for (int s = 128; s > 0; s >>= 1) {
        if (t < s) {
            float od = sdist[t + s]; int oi = sidx[t + s];
            if (od < sdist[t] || (od == sdist[t] && oi < sidx[t])) {
                sdist[t] = od; sidx[t] = oi;
            }
        }
        __syncthreads();
    }
    int idx = sidx[0];

    float q = emb[(size_t)idx * 256 + t];
    out[((size_t)(b * 256 + t) * 8 + y) * 8 + xx] = q;
    float diff = q - lat[t];
    __syncthreads();
    sdist[t] = diff * diff;
    __syncthreads();
    for (int s = 128; s > 0; s >>= 1) {
        if (t < s) sdist[t] += sdist[t + s];
        __syncthreads();
    }
    if (t == 0) {
        atomicAdd(mse_acc, sdist[0]);
        atomicAdd(&hist[idx], 1);
    }
}

__global__ void final_k(const float* __restrict__ mse_acc, const int* __restrict__ hist,
                        float* __restrict__ out)
{
    __shared__ float sh[512];
    int t = threadIdx.x;
    float p = (float)hist[t] / 512.f;
    sh[t] = p * logf(p + 1e-10f);
    __syncthreads();
    for (int s = 256; s > 0; s >>= 1) {
        if (t < s) sh[t] += sh[t + s];
        __syncthreads();
    }
    if (t == 0) {
        float loss = 2.f * mse_acc[0] / (512.f * 256.f);
        float perp = expf(-sh[0]);
        out[131072] = loss;
        out[131073] = perp;
    }
}

// ===========================================================================
extern "C" void kernel_launch(void* const* d_in, const int* in_sizes, int n_in,
                              void* d_out, int out_size, void* d_ws, size_t ws_size,
                              hipStream_t stream)
{
    const float* x    = (const float*)d_in[0];
    const float* w_in = (const float*)d_in[1];
    const float* b_in = (const float*)d_in[2];
    const float* w_h1 = (const float*)d_in[3];
    const float* b_h1 = (const float*)d_in[4];
    const float* w_h2 = (const float*)d_in[5];
    const float* b_h2 = (const float*)d_in[6];
    const float* w_h3 = (const float*)d_in[7];
    const float* b_h3 = (const float*)d_in[8];
    const float* r0w1 = (const float*)d_in[9];
    const float* r0w2 = (const float*)d_in[10];
    const float* r1w1 = (const float*)d_in[11];
    const float* r1w2 = (const float*)d_in[12];
    const float* emb  = (const float*)d_in[13];
    float* out = (float*)d_out;

    char* ws = (char*)d_ws;
    size_t off = 0;
    auto alloc = [&](size_t bytes) -> void* {
        void* p = ws + off;
        off += (bytes + 255) & ~(size_t)255;
        return p;
    };

    float* en  = (float*)alloc(512 * 4);
    float* mse = (float*)alloc(256);
    int*  hist = (int*)alloc(512 * 4);
    float* p3  = (float*)alloc(524288ull * 4);
    bf16* h3T  = (bf16*)alloc(524288ull * 2);
    bf16* h4T  = (bf16*)alloc(131072ull * 2);
    bf16* t1T  = (bf16*)alloc(524288ull * 2);
    bf16* h5T  = (bf16*)alloc(131072ull * 2);
    bf16* h6T  = (bf16*)alloc(131072ull * 2);
    bf16* wp1  = (bf16*)alloc(8192ull * 2);
    bf16* wpack2 = (bf16*)alloc(1638400ull * 2);
    bf16* wpack3 = (bf16*)alloc(3276800ull * 2);
    bf16* wp4  = (bf16*)alloc(589824ull * 2);
    bf16* wpA0 = (bf16*)alloc(786432ull * 2);
    bf16* wpA1 = (bf16*)alloc(786432ull * 2);
    bf16* wpB0 = (bf16*)alloc(262144ull * 2);
    bf16* wpB1 = (bf16*)alloc(262144ull * 2);
    bf16* h2c  = (bf16*)alloc(8388608ull * 2);     // [8][16 blk][4096 px][16]
    size_t base_end = off;

    const size_t P2S_B = 16777216ull * 2;          // conv2 slices, 33.5 MB
    const size_t H1F_B = 8388608ull * 8 * 2;       // batched h1c, 134 MB
    size_t needT0 = base_end + P2S_B + H1F_B + 4096;
    size_t needT1 = base_end + H1F_B + 4096;
    bf16* p2s = nullptr;
    bf16* h1c;
    int tier;
    if (ws_size >= needT0) {
        p2s = (bf16*)alloc(P2S_B);
        h1c = (bf16*)alloc(H1F_B);
        tier = 0;
    } else if (ws_size >= needT1) {
        h1c = (bf16*)alloc(H1F_B);
        tier = 1;
    } else {
        h1c = (bf16*)alloc(8388608ull * 2);
        tier = 2;
    }

    init_k<<<31781, 256, 0, stream>>>(w_in, w_h1, w_h2, w_h3, r0w1, r0w2, r1w1, r1w2,
        emb, wp1, wpack2, wpack3, wp4, wpA0, wpA1, wpB0, wpB1, en, mse, hist, p3);

    if (tier == 0) {
        conv1m_k<<<4096, 256, 0, stream>>>(x, wp1, b_in, h1c);
        conv_mfma5_k<256, 64, 128, 2, 2><<<1024, 256, 0, stream>>>(
            h1c, wpack2, nullptr, nullptr, p2s);
        combine2_k<<<32768, 256, 0, stream>>>(p2s, b_h1, h2c);
    } else if (tier == 1) {
        conv1m_k<<<4096, 256, 0, stream>>>(x, wp1, b_in, h1c);
        conv_mfma5_k<256, 64, 128, 1, 0><<<512, 256, 0, stream>>>(
            h1c, wpack2, b_h1, nullptr, h2c);
    } else {
        for (int n = 0; n < 8; ++n) {
            conv1m_k<<<512, 256, 0, stream>>>(x + (size_t)n * 786432, wp1, b_in, h1c);
            conv_mfma5_k<256, 64, 128, 1, 0><<<64, 256, 0, stream>>>(
                h1c, wpack2, b_h1, nullptr, h2c + (size_t)n * 1048576);
        }
    }

    conv_mfma5_k<64, 16, 256, 8, 1><<<256, 256, 0, stream>>>(
        h2c, wpack3, b_h2, p3, nullptr);
    combine3_k<<<2048, 256, 0, stream>>>(p3, b_h2, h3T);

    conv4m_k<<<8, 256, 0, stream>>>(h3T, wp4, b_h3, h4T);
    resam_k<<<32, 256, 0, stream>>>(h4T, wpA0, t1T);
    resbm_k<<<8, 256, 0, stream>>>(h4T, t1T, wpB0, h5T);
    resam_k<<<32, 256, 0, stream>>>(h5T, wpA1, t1T);
    resbm_k<<<8, 256, 0, stream>>>(h5T, t1T, wpB1, h6T);

    vq_k<<<512, 256, 0, stream>>>(h6T, emb, en, out, mse, hist);
    final_k<<<1, 512, 0, stream>>>(mse, hist, out);
}